// Round 1
// baseline (655.932 us; speedup 1.0000x reference)
//
#include <hip/hip_runtime.h>

#define N_NODES 50000
#define N_EDGES 400000
#define F_INP 5
#define HD 256          // HEADS*DIM = 2*128
#define BN_EPS 1e-5f

// ---- workspace layout (float offsets) ----
#define OFF_HBN   0            // N*5        = 250000
#define OFF_LOG   250000       // E*2        = 800000   (logits, then ex in-place)
#define OFF_MX    1050000      // N*2 (uint) = 100000
#define OFF_SSUM  1150000      // N*256      = 12800000
#define OFF_DEN   13950000     // N*2        = 100000
#define OFF_CNT   14050000     // N          = 50000
// total 14100000 floats = 56.4 MB

__device__ __forceinline__ unsigned ord_enc(float f) {
    unsigned u = __float_as_uint(f);
    return (u & 0x80000000u) ? ~u : (u | 0x80000000u);
}
__device__ __forceinline__ float ord_dec(unsigned u) {
    return (u & 0x80000000u) ? __uint_as_float(u & 0x7FFFFFFFu)
                             : __uint_as_float(~u);
}

__global__ void k_init_mx(unsigned* __restrict__ mx) {
    int i = blockIdx.x * blockDim.x + threadIdx.x;
    if (i < N_NODES * 2) mx[i] = 0x007FFFFFu;   // ord_enc(-inf)
}

// BN1 on input features -> hbn [N,5]
__global__ void k_bn1(const float* __restrict__ h, const float* __restrict__ g1,
                      const float* __restrict__ be1, const float* __restrict__ rm1,
                      const float* __restrict__ rv1, float* __restrict__ hbn) {
    int i = blockIdx.x * blockDim.x + threadIdx.x;
    if (i >= N_NODES * F_INP) return;
    int f = i % F_INP;
    hbn[i] = (h[i] - rm1[f]) * rsqrtf(rv1[f] + BN_EPS) * g1[f] + be1[f];
}

// one wave per edge: logits[e,h], atomicMax per dst, degree count
__global__ void k_edge_logits(const float* __restrict__ hbn, const int* __restrict__ ei,
                              const float* __restrict__ ew,
                              const float* __restrict__ Wl, const float* __restrict__ bl,
                              const float* __restrict__ Wr, const float* __restrict__ br,
                              const float* __restrict__ We, const float* __restrict__ att,
                              float* __restrict__ logits, unsigned* __restrict__ mx,
                              float* __restrict__ cnt) {
    int wid = (int)((blockIdx.x * blockDim.x + threadIdx.x) >> 6);
    int lane = threadIdx.x & 63;
    if (wid >= N_EDGES) return;
    int src = ei[wid], dst = ei[N_EDGES + wid];
    float w = ew[wid];
    float hs[F_INP], hdd[F_INP];
#pragma unroll
    for (int f = 0; f < F_INP; ++f) { hs[f] = hbn[src * F_INP + f]; hdd[f] = hbn[dst * F_INP + f]; }
    float part0 = 0.f, part1 = 0.f;
#pragma unroll
    for (int hh = 0; hh < 2; ++hh) {
        float acc = 0.f;
#pragma unroll
        for (int p = 0; p < 2; ++p) {
            int c = hh * 128 + p * 64 + lane;
            float xl = bl[c], xr = br[c];
#pragma unroll
            for (int f = 0; f < F_INP; ++f) {
                xl += hs[f] * Wl[f * HD + c];
                xr += hdd[f] * Wr[f * HD + c];
            }
            float z = xl + xr + w * We[c];
            z = z > 0.f ? z : 0.2f * z;
            acc += att[c] * z;
        }
        if (hh == 0) part0 = acc; else part1 = acc;
    }
#pragma unroll
    for (int m = 32; m; m >>= 1) {
        part0 += __shfl_xor(part0, m);
        part1 += __shfl_xor(part1, m);
    }
    if (lane == 0) {
        logits[wid * 2 + 0] = part0;
        logits[wid * 2 + 1] = part1;
        atomicMax(&mx[dst * 2 + 0], ord_enc(part0));
        atomicMax(&mx[dst * 2 + 1], ord_enc(part1));
        atomicAdd(&cnt[dst], 1.0f);
    }
}

// ex = exp(logit - mx[dst]); den += ex  (ex written over logits)
__global__ void k_exp_den(const int* __restrict__ ei, float* __restrict__ logits,
                          const unsigned* __restrict__ mx, float* __restrict__ den) {
    int i = blockIdx.x * blockDim.x + threadIdx.x;
    if (i >= N_EDGES * 2) return;
    int e = i >> 1, hh = i & 1;
    int dst = ei[N_EDGES + e];
    float exv = __expf(logits[i] - ord_dec(mx[dst * 2 + hh]));
    logits[i] = exv;
    atomicAdd(&den[dst * 2 + hh], exv);
}

// one wave per edge: recompute xl[src], scatter alpha-weighted message into ssum
__global__ void k_scatter(const float* __restrict__ hbn, const int* __restrict__ ei,
                          const float* __restrict__ ex, const float* __restrict__ den,
                          const float* __restrict__ Wl, const float* __restrict__ bl,
                          float* __restrict__ ssum) {
    int wid = (int)((blockIdx.x * blockDim.x + threadIdx.x) >> 6);
    int lane = threadIdx.x & 63;
    if (wid >= N_EDGES) return;
    int src = ei[wid], dst = ei[N_EDGES + wid];
    float a0 = ex[wid * 2 + 0] / (den[dst * 2 + 0] + 1e-16f);
    float a1 = ex[wid * 2 + 1] / (den[dst * 2 + 1] + 1e-16f);
    float hs[F_INP];
#pragma unroll
    for (int f = 0; f < F_INP; ++f) hs[f] = hbn[src * F_INP + f];
#pragma unroll
    for (int hh = 0; hh < 2; ++hh) {
        float al = hh ? a1 : a0;
#pragma unroll
        for (int p = 0; p < 2; ++p) {
            int c = hh * 128 + p * 64 + lane;
            float xl = bl[c];
#pragma unroll
            for (int f = 0; f < F_INP; ++f) xl += hs[f] * Wl[f * HD + c];
            atomicAdd(&ssum[dst * HD + c], xl * al);
        }
    }
}

// fused: head-mean/deg-mean + bias -> fc1(LDS W1) -> BN2 -> lrelu -> fc2 -> out
__launch_bounds__(256, 1)
__global__ void k_mlp(const float* __restrict__ ssum, const float* __restrict__ cnt,
                      const float* __restrict__ bias_gat,
                      const float* __restrict__ W1, const float* __restrict__ b1,
                      const float* __restrict__ g2, const float* __restrict__ be2,
                      const float* __restrict__ rm2, const float* __restrict__ rv2,
                      const float* __restrict__ W2, const float* __restrict__ b2,
                      float* __restrict__ out) {
    __shared__ float wsh[128 * 128];
    __shared__ float xsh[8][128];
    int t = threadIdx.x;
    for (int i = t; i < 128 * 128 / 4; i += 256)
        ((float4*)wsh)[i] = ((const float4*)W1)[i];
    __syncthreads();

    int nl = t >> 5;      // local node 0..7
    int jg = t & 31;      // 4-wide output group
    int j4 = jg * 4;

    const int ngroups = (N_NODES + 7) / 8;
    for (int g = blockIdx.x; g < ngroups; g += gridDim.x) {
        int n = g * 8 + nl;
        bool valid = n < N_NODES;
        if (valid) {
            float inv = 1.0f / fmaxf(cnt[n], 1.0f);
            float4 s0 = *(const float4*)&ssum[n * HD + j4];
            float4 s1 = *(const float4*)&ssum[n * HD + 128 + j4];
            float4 bg = *(const float4*)&bias_gat[j4];
            xsh[nl][j4 + 0] = (s0.x + s1.x) * 0.5f * inv + bg.x;
            xsh[nl][j4 + 1] = (s0.y + s1.y) * 0.5f * inv + bg.y;
            xsh[nl][j4 + 2] = (s0.z + s1.z) * 0.5f * inv + bg.z;
            xsh[nl][j4 + 3] = (s0.w + s1.w) * 0.5f * inv + bg.w;
        }
        __syncthreads();
        if (valid) {
            float4 acc = *(const float4*)&b1[j4];
#pragma unroll 8
            for (int k = 0; k < 128; ++k) {
                float xv = xsh[nl][k];
                float4 w = *(const float4*)&wsh[k * 128 + j4];
                acc.x += xv * w.x; acc.y += xv * w.y;
                acc.z += xv * w.z; acc.w += xv * w.w;
            }
            float4 rm = *(const float4*)&rm2[j4];
            float4 rv = *(const float4*)&rv2[j4];
            float4 gg = *(const float4*)&g2[j4];
            float4 bb = *(const float4*)&be2[j4];
            float a[4];
            a[0] = (acc.x - rm.x) * rsqrtf(rv.x + BN_EPS) * gg.x + bb.x;
            a[1] = (acc.y - rm.y) * rsqrtf(rv.y + BN_EPS) * gg.y + bb.y;
            a[2] = (acc.z - rm.z) * rsqrtf(rv.z + BN_EPS) * gg.z + bb.z;
            a[3] = (acc.w - rm.w) * rsqrtf(rv.w + BN_EPS) * gg.w + bb.w;
#pragma unroll
            for (int q = 0; q < 4; ++q) a[q] = a[q] > 0.f ? a[q] : 0.01f * a[q];
            float pf[5] = {0.f, 0.f, 0.f, 0.f, 0.f};
#pragma unroll
            for (int q = 0; q < 4; ++q)
#pragma unroll
                for (int f = 0; f < 5; ++f) pf[f] += a[q] * W2[(j4 + q) * 5 + f];
#pragma unroll
            for (int m = 16; m; m >>= 1)
#pragma unroll
                for (int f = 0; f < 5; ++f) pf[f] += __shfl_xor(pf[f], m);
            if (jg == 0) {
#pragma unroll
                for (int f = 0; f < 5; ++f) out[n * 5 + f] = pf[f] + b2[f];
            }
        }
        __syncthreads();
    }
}

extern "C" void kernel_launch(void* const* d_in, const int* in_sizes, int n_in,
                              void* d_out, int out_size, void* d_ws, size_t ws_size,
                              hipStream_t stream) {
    const float* h    = (const float*)d_in[0];
    const int*   ei   = (const int*)d_in[1];
    const float* ew   = (const float*)d_in[2];
    const float* g1   = (const float*)d_in[3];
    const float* be1  = (const float*)d_in[4];
    const float* rm1  = (const float*)d_in[5];
    const float* rv1  = (const float*)d_in[6];
    const float* Wl   = (const float*)d_in[7];
    const float* bl   = (const float*)d_in[8];
    const float* Wr   = (const float*)d_in[9];
    const float* br   = (const float*)d_in[10];
    const float* We   = (const float*)d_in[11];
    const float* att  = (const float*)d_in[12];
    const float* bias_gat = (const float*)d_in[13];
    const float* W1   = (const float*)d_in[14];
    const float* b1   = (const float*)d_in[15];
    const float* g2   = (const float*)d_in[16];
    const float* be2  = (const float*)d_in[17];
    const float* rm2  = (const float*)d_in[18];
    const float* rv2  = (const float*)d_in[19];
    const float* W2   = (const float*)d_in[20];
    const float* b2   = (const float*)d_in[21];

    float* ws = (float*)d_ws;
    float*    hbn    = ws + OFF_HBN;
    float*    logits = ws + OFF_LOG;
    unsigned* mx     = (unsigned*)(ws + OFF_MX);
    float*    ssum   = ws + OFF_SSUM;
    float*    den    = ws + OFF_DEN;
    float*    cnt    = ws + OFF_CNT;

    // zero ssum/den/cnt (contiguous), init mx to -inf encoding
    hipMemsetAsync(ws + OFF_SSUM, 0, (size_t)(12800000 + 100000 + 50000) * 4, stream);
    k_init_mx<<<(N_NODES * 2 + 255) / 256, 256, 0, stream>>>(mx);
    k_bn1<<<(N_NODES * F_INP + 255) / 256, 256, 0, stream>>>(h, g1, be1, rm1, rv1, hbn);
    k_edge_logits<<<(N_EDGES + 3) / 4, 256, 0, stream>>>(hbn, ei, ew, Wl, bl, Wr, br, We, att,
                                                         logits, mx, cnt);
    k_exp_den<<<(N_EDGES * 2 + 255) / 256, 256, 0, stream>>>(ei, logits, mx, den);
    k_scatter<<<(N_EDGES + 3) / 4, 256, 0, stream>>>(hbn, ei, logits, den, Wl, bl, ssum);
    k_mlp<<<512, 256, 0, stream>>>(ssum, cnt, bias_gat, W1, b1, g2, be2, rm2, rv2, W2, b2,
                                   (float*)d_out);
}

// Round 2
// 266.313 us; speedup vs baseline: 2.4630x; 2.4630x over previous
//
#include <hip/hip_runtime.h>

#define N_NODES 50000
#define N_EDGES 400000
#define F_INP 5
#define HD 256          // HEADS*DIM = 2*128
#define BN_EPS 1e-5f

// ---- workspace layout (float offsets) ----
#define OFF_HBN   0            // N*5  = 250000
#define OFF_ACC   250000       // N*16 = 800000  (per node: den0,S0[5],den1,S1[5],cnt,pad3)
// total 1,050,000 floats = 4.2 MB

// BN1 on input features -> hbn [N,5]
__global__ void k_bn1(const float* __restrict__ h, const float* __restrict__ g1,
                      const float* __restrict__ be1, const float* __restrict__ rm1,
                      const float* __restrict__ rv1, float* __restrict__ hbn) {
    int i = blockIdx.x * blockDim.x + threadIdx.x;
    if (i >= N_NODES * F_INP) return;
    int f = i % F_INP;
    hbn[i] = (h[i] - rm1[f]) * rsqrtf(rv1[f] + BN_EPS) * g1[f] + be1[f];
}

// One wave per edge, single fused pass:
// logits (no max subtraction) -> ex = exp(logit) -> scatter 13 moments per edge.
__global__ void k_edge(const float* __restrict__ hbn, const int* __restrict__ ei,
                       const float* __restrict__ ew,
                       const float* __restrict__ Wl, const float* __restrict__ bl,
                       const float* __restrict__ Wr, const float* __restrict__ br,
                       const float* __restrict__ We, const float* __restrict__ att,
                       float* __restrict__ acc) {
    int wid = (int)((blockIdx.x * blockDim.x + threadIdx.x) >> 6);
    int lane = threadIdx.x & 63;
    if (wid >= N_EDGES) return;
    int src = ei[wid], dst = ei[N_EDGES + wid];
    float w = ew[wid];
    float hs[F_INP], hdd[F_INP];
#pragma unroll
    for (int f = 0; f < F_INP; ++f) {
        hs[f]  = hbn[src * F_INP + f];
        hdd[f] = hbn[dst * F_INP + f];
    }
    float part0 = 0.f, part1 = 0.f;
#pragma unroll
    for (int p = 0; p < 4; ++p) {
        int c = p * 64 + lane;                 // p<2 -> head0, p>=2 -> head1
        float xl = bl[c], xr = br[c];
#pragma unroll
        for (int f = 0; f < F_INP; ++f) {
            xl += hs[f]  * Wl[f * HD + c];
            xr += hdd[f] * Wr[f * HD + c];
        }
        float z = xl + xr + w * We[c];
        z = z > 0.f ? z : 0.2f * z;
        float a = att[c] * z;
        if (p < 2) part0 += a; else part1 += a;
    }
#pragma unroll
    for (int m = 32; m; m >>= 1) {
        part0 += __shfl_xor(part0, m);
        part1 += __shfl_xor(part1, m);
    }
    float ex0 = __expf(part0), ex1 = __expf(part1);
    if (lane < 13) {
        float v;
        if (lane == 0)       v = ex0;
        else if (lane < 6)   v = ex0 * hs[lane - 1];
        else if (lane == 6)  v = ex1;
        else if (lane < 12)  v = ex1 * hs[lane - 7];
        else                 v = 1.0f;           // degree count
        atomicAdd(&acc[dst * 16 + lane], v);
    }
}

// fused: reconstruct aggregated feature from 12 moments -> fc1(LDS W1) -> BN2
//        -> lrelu -> fc2 -> out
__launch_bounds__(256, 1)
__global__ void k_mlp(const float* __restrict__ acc,
                      const float* __restrict__ Wl, const float* __restrict__ bl,
                      const float* __restrict__ bias_gat,
                      const float* __restrict__ W1, const float* __restrict__ b1,
                      const float* __restrict__ g2, const float* __restrict__ be2,
                      const float* __restrict__ rm2, const float* __restrict__ rv2,
                      const float* __restrict__ W2, const float* __restrict__ b2,
                      float* __restrict__ out) {
    __shared__ float wsh[128 * 128];
    __shared__ float xsh[8][128];
    __shared__ float wlsh[5 * 256 + 256 + 128];   // Wl | bl | bias_gat
    __shared__ float accsh[8][16];
    int t = threadIdx.x;
    for (int i = t; i < 128 * 128 / 4; i += 256)
        ((float4*)wsh)[i] = ((const float4*)W1)[i];
    for (int i = t; i < 5 * 256; i += 256) wlsh[i] = Wl[i];
    wlsh[1280 + t] = bl[t];
    if (t < 128) wlsh[1536 + t] = bias_gat[t];
    __syncthreads();
    const float* WL = wlsh;
    const float* BL = wlsh + 1280;
    const float* BG = wlsh + 1536;

    int nl = t >> 5;      // local node 0..7
    int jg = t & 31;      // output group
    int j4 = jg * 4;

    const int ngroups = (N_NODES + 7) / 8;
    for (int g = blockIdx.x; g < ngroups; g += gridDim.x) {
        int n = g * 8 + nl;
        if (t < 128) {
            int node = g * 8 + (t >> 4);
            accsh[t >> 4][t & 15] = (node < N_NODES) ? acc[node * 16 + (t & 15)] : 0.f;
        }
        __syncthreads();
        bool valid = n < N_NODES;
        if (valid) {
            float den0 = accsh[nl][0], den1 = accsh[nl][6], cntv = accsh[nl][12];
            float r0 = 1.f / (den0 + 1e-16f), r1 = 1.f / (den1 + 1e-16f);
            float scale = 0.5f / fmaxf(cntv, 1.f);
            float c0 = den0 * r0 * scale, c1 = den1 * r1 * scale;
            float T0[F_INP], T1[F_INP];
#pragma unroll
            for (int f = 0; f < F_INP; ++f) {
                T0[f] = accsh[nl][1 + f] * r0 * scale;
                T1[f] = accsh[nl][7 + f] * r1 * scale;
            }
            // x[d] = 0.5/cnt * (ssum_h0[d] + ssum_h1[d]) + bias_gat[d]
#pragma unroll
            for (int q = 0; q < 4; ++q) {
                int d = j4 + q;
                float xv = c0 * BL[d] + c1 * BL[128 + d];
#pragma unroll
                for (int f = 0; f < F_INP; ++f)
                    xv += T0[f] * WL[f * HD + d] + T1[f] * WL[f * HD + 128 + d];
                xsh[nl][d] = xv + BG[d];
            }
            // fc1 (same-half-wave producer/consumer, no barrier needed)
            float4 a4 = *(const float4*)&b1[j4];
#pragma unroll 8
            for (int k = 0; k < 128; ++k) {
                float xv = xsh[nl][k];
                float4 w = *(const float4*)&wsh[k * 128 + j4];
                a4.x += xv * w.x; a4.y += xv * w.y;
                a4.z += xv * w.z; a4.w += xv * w.w;
            }
            float4 rm = *(const float4*)&rm2[j4];
            float4 rv = *(const float4*)&rv2[j4];
            float4 gg = *(const float4*)&g2[j4];
            float4 bb = *(const float4*)&be2[j4];
            float a[4];
            a[0] = (a4.x - rm.x) * rsqrtf(rv.x + BN_EPS) * gg.x + bb.x;
            a[1] = (a4.y - rm.y) * rsqrtf(rv.y + BN_EPS) * gg.y + bb.y;
            a[2] = (a4.z - rm.z) * rsqrtf(rv.z + BN_EPS) * gg.z + bb.z;
            a[3] = (a4.w - rm.w) * rsqrtf(rv.w + BN_EPS) * gg.w + bb.w;
#pragma unroll
            for (int q = 0; q < 4; ++q) a[q] = a[q] > 0.f ? a[q] : 0.01f * a[q];
            float pf[5] = {0.f, 0.f, 0.f, 0.f, 0.f};
#pragma unroll
            for (int q = 0; q < 4; ++q)
#pragma unroll
                for (int f = 0; f < 5; ++f) pf[f] += a[q] * W2[(j4 + q) * 5 + f];
#pragma unroll
            for (int m = 16; m; m >>= 1)
#pragma unroll
                for (int f = 0; f < 5; ++f) pf[f] += __shfl_xor(pf[f], m);
            if (jg == 0) {
#pragma unroll
                for (int f = 0; f < 5; ++f) out[n * 5 + f] = pf[f] + b2[f];
            }
        }
        __syncthreads();
    }
}

extern "C" void kernel_launch(void* const* d_in, const int* in_sizes, int n_in,
                              void* d_out, int out_size, void* d_ws, size_t ws_size,
                              hipStream_t stream) {
    const float* h    = (const float*)d_in[0];
    const int*   ei   = (const int*)d_in[1];
    const float* ew   = (const float*)d_in[2];
    const float* g1   = (const float*)d_in[3];
    const float* be1  = (const float*)d_in[4];
    const float* rm1  = (const float*)d_in[5];
    const float* rv1  = (const float*)d_in[6];
    const float* Wl   = (const float*)d_in[7];
    const float* bl   = (const float*)d_in[8];
    const float* Wr   = (const float*)d_in[9];
    const float* br   = (const float*)d_in[10];
    const float* We   = (const float*)d_in[11];
    const float* att  = (const float*)d_in[12];
    const float* bias_gat = (const float*)d_in[13];
    const float* W1   = (const float*)d_in[14];
    const float* b1   = (const float*)d_in[15];
    const float* g2   = (const float*)d_in[16];
    const float* be2  = (const float*)d_in[17];
    const float* rm2  = (const float*)d_in[18];
    const float* rv2  = (const float*)d_in[19];
    const float* W2   = (const float*)d_in[20];
    const float* b2   = (const float*)d_in[21];

    float* ws  = (float*)d_ws;
    float* hbn = ws + OFF_HBN;
    float* acc = ws + OFF_ACC;

    hipMemsetAsync(acc, 0, (size_t)N_NODES * 16 * 4, stream);
    k_bn1<<<(N_NODES * F_INP + 255) / 256, 256, 0, stream>>>(h, g1, be1, rm1, rv1, hbn);
    k_edge<<<(N_EDGES + 3) / 4, 256, 0, stream>>>(hbn, ei, ew, Wl, bl, Wr, br, We, att, acc);
    k_mlp<<<512, 256, 0, stream>>>(acc, Wl, bl, bias_gat, W1, b1, g2, be2, rm2, rv2, W2, b2,
                                   (float*)d_out);
}

// Round 3
// 162.012 us; speedup vs baseline: 4.0487x; 1.6438x over previous
//
#include <hip/hip_runtime.h>

#define N_NODES 50000
#define N_EDGES 400000
#define F_INP 5
#define HD 256          // HEADS*DIM = 2*128
#define BN_EPS 1e-5f

// ---- workspace layout (float offsets) ----
#define OFF_HBN   0            // N*8  = 400000 (padded rows: 5 used + 3 pad)
#define OFF_ACC   400000       // N*16 = 800000 (per node: den0,S0[5],den1,S1[5],cnt,pad3)

// BN1 on input features -> hbn8 [N,8] (padded for aligned float4 loads)
__global__ void k_bn1(const float* __restrict__ h, const float* __restrict__ g1,
                      const float* __restrict__ be1, const float* __restrict__ rm1,
                      const float* __restrict__ rv1, float* __restrict__ hbn8) {
    int i = blockIdx.x * blockDim.x + threadIdx.x;
    if (i >= N_NODES * 8) return;
    int f = i & 7, n = i >> 3;
    float v = 0.f;
    if (f < F_INP) {
        float x = h[n * F_INP + f];
        v = (x - rm1[f]) * rsqrtf(rv1[f] + BN_EPS) * g1[f] + be1[f];
    }
    hbn8[i] = v;
}

// Persistent waves, one edge per wave-iteration; per-channel weights hoisted
// into registers once per wave. lane owns channels c = p*64+lane, p=0..3
// (p<2 -> head0, p>=2 -> head1).
__launch_bounds__(256)
__global__ void k_edge(const float* __restrict__ hbn8, const int* __restrict__ ei,
                       const float* __restrict__ ew,
                       const float* __restrict__ Wl, const float* __restrict__ bl,
                       const float* __restrict__ Wr, const float* __restrict__ br,
                       const float* __restrict__ We, const float* __restrict__ att,
                       float* __restrict__ acc) {
    int lane = threadIdx.x & 63;
    int wave = (int)((blockIdx.x * blockDim.x + threadIdx.x) >> 6);
    int nwaves = (int)((gridDim.x * blockDim.x) >> 6);

    float wa[4][F_INP], wb[4][F_INP], cb[4], wev[4], at[4];
#pragma unroll
    for (int p = 0; p < 4; ++p) {
        int c = p * 64 + lane;
        cb[p] = bl[c] + br[c];
        wev[p] = We[c];
        at[p] = att[c];
#pragma unroll
        for (int f = 0; f < F_INP; ++f) {
            wa[p][f] = Wl[f * HD + c];
            wb[p][f] = Wr[f * HD + c];
        }
    }

    for (int e = wave; e < N_EDGES; e += nwaves) {
        int src = ei[e], dst = ei[N_EDGES + e];
        float w = ew[e];
        float4 hs = *(const float4*)&hbn8[src * 8];
        float  hs4 = hbn8[src * 8 + 4];
        float4 hd = *(const float4*)&hbn8[dst * 8];
        float  hd4 = hbn8[dst * 8 + 4];

        float part0 = 0.f, part1 = 0.f;
#pragma unroll
        for (int p = 0; p < 4; ++p) {
            float u = cb[p] + w * wev[p];
            u += hs.x * wa[p][0] + hs.y * wa[p][1] + hs.z * wa[p][2]
               + hs.w * wa[p][3] + hs4 * wa[p][4];
            u += hd.x * wb[p][0] + hd.y * wb[p][1] + hd.z * wb[p][2]
               + hd.w * wb[p][3] + hd4 * wb[p][4];
            float z = fmaxf(u, 0.2f * u);        // leaky_relu slope 0.2
            float a = at[p] * z;
            if (p < 2) part0 += a; else part1 += a;
        }
#pragma unroll
        for (int m = 32; m; m >>= 1) {
            part0 += __shfl_xor(part0, m);
            part1 += __shfl_xor(part1, m);
        }
        float ex0 = __expf(part0), ex1 = __expf(part1);
        if (lane < 13) {
            int k = (lane < 6) ? lane - 1 : lane - 7;
            float hsel = hs.x;
            hsel = (k == 1) ? hs.y : hsel;
            hsel = (k == 2) ? hs.z : hsel;
            hsel = (k == 3) ? hs.w : hsel;
            hsel = (k == 4) ? hs4  : hsel;
            float v = ((lane < 6) ? ex0 : ex1) * hsel;
            v = (lane == 0)  ? ex0 : v;
            v = (lane == 6)  ? ex1 : v;
            v = (lane == 12) ? 1.0f : v;
            atomicAdd(&acc[dst * 16 + lane], v);
        }
    }
}

// fused: reconstruct aggregated feature from 12 moments -> fc1(LDS W1) -> BN2
//        -> lrelu -> fc2 -> out
__launch_bounds__(256, 1)
__global__ void k_mlp(const float* __restrict__ acc,
                      const float* __restrict__ Wl, const float* __restrict__ bl,
                      const float* __restrict__ bias_gat,
                      const float* __restrict__ W1, const float* __restrict__ b1,
                      const float* __restrict__ g2, const float* __restrict__ be2,
                      const float* __restrict__ rm2, const float* __restrict__ rv2,
                      const float* __restrict__ W2, const float* __restrict__ b2,
                      float* __restrict__ out) {
    __shared__ float wsh[128 * 128];
    __shared__ float xsh[8][128];
    __shared__ float wlsh[5 * 256 + 256 + 128];   // Wl | bl | bias_gat
    __shared__ float accsh[8][16];
    int t = threadIdx.x;
    for (int i = t; i < 128 * 128 / 4; i += 256)
        ((float4*)wsh)[i] = ((const float4*)W1)[i];
    for (int i = t; i < 5 * 256; i += 256) wlsh[i] = Wl[i];
    wlsh[1280 + t] = bl[t];
    if (t < 128) wlsh[1536 + t] = bias_gat[t];
    __syncthreads();
    const float* WL = wlsh;
    const float* BL = wlsh + 1280;
    const float* BG = wlsh + 1536;

    int nl = t >> 5;      // local node 0..7
    int jg = t & 31;      // output group
    int j4 = jg * 4;

    const int ngroups = (N_NODES + 7) / 8;
    for (int g = blockIdx.x; g < ngroups; g += gridDim.x) {
        int n = g * 8 + nl;
        if (t < 128) {
            int node = g * 8 + (t >> 4);
            accsh[t >> 4][t & 15] = (node < N_NODES) ? acc[node * 16 + (t & 15)] : 0.f;
        }
        __syncthreads();
        bool valid = n < N_NODES;
        if (valid) {
            float den0 = accsh[nl][0], den1 = accsh[nl][6], cntv = accsh[nl][12];
            float r0 = 1.f / (den0 + 1e-16f), r1 = 1.f / (den1 + 1e-16f);
            float scale = 0.5f / fmaxf(cntv, 1.f);
            float c0 = den0 * r0 * scale, c1 = den1 * r1 * scale;
            float T0[F_INP], T1[F_INP];
#pragma unroll
            for (int f = 0; f < F_INP; ++f) {
                T0[f] = accsh[nl][1 + f] * r0 * scale;
                T1[f] = accsh[nl][7 + f] * r1 * scale;
            }
#pragma unroll
            for (int q = 0; q < 4; ++q) {
                int d = j4 + q;
                float xv = c0 * BL[d] + c1 * BL[128 + d];
#pragma unroll
                for (int f = 0; f < F_INP; ++f)
                    xv += T0[f] * WL[f * HD + d] + T1[f] * WL[f * HD + 128 + d];
                xsh[nl][d] = xv + BG[d];
            }
            float4 a4 = *(const float4*)&b1[j4];
#pragma unroll 8
            for (int k = 0; k < 128; ++k) {
                float xv = xsh[nl][k];
                float4 w = *(const float4*)&wsh[k * 128 + j4];
                a4.x += xv * w.x; a4.y += xv * w.y;
                a4.z += xv * w.z; a4.w += xv * w.w;
            }
            float4 rm = *(const float4*)&rm2[j4];
            float4 rv = *(const float4*)&rv2[j4];
            float4 gg = *(const float4*)&g2[j4];
            float4 bb = *(const float4*)&be2[j4];
            float a[4];
            a[0] = (a4.x - rm.x) * rsqrtf(rv.x + BN_EPS) * gg.x + bb.x;
            a[1] = (a4.y - rm.y) * rsqrtf(rv.y + BN_EPS) * gg.y + bb.y;
            a[2] = (a4.z - rm.z) * rsqrtf(rv.z + BN_EPS) * gg.z + bb.z;
            a[3] = (a4.w - rm.w) * rsqrtf(rv.w + BN_EPS) * gg.w + bb.w;
#pragma unroll
            for (int q = 0; q < 4; ++q) a[q] = fmaxf(a[q], 0.01f * a[q]);
            float pf[5] = {0.f, 0.f, 0.f, 0.f, 0.f};
#pragma unroll
            for (int q = 0; q < 4; ++q)
#pragma unroll
                for (int f = 0; f < 5; ++f) pf[f] += a[q] * W2[(j4 + q) * 5 + f];
#pragma unroll
            for (int m = 16; m; m >>= 1)
#pragma unroll
                for (int f = 0; f < 5; ++f) pf[f] += __shfl_xor(pf[f], m);
            if (jg == 0) {
#pragma unroll
                for (int f = 0; f < 5; ++f) out[n * 5 + f] = pf[f] + b2[f];
            }
        }
        __syncthreads();
    }
}

extern "C" void kernel_launch(void* const* d_in, const int* in_sizes, int n_in,
                              void* d_out, int out_size, void* d_ws, size_t ws_size,
                              hipStream_t stream) {
    const float* h    = (const float*)d_in[0];
    const int*   ei   = (const int*)d_in[1];
    const float* ew   = (const float*)d_in[2];
    const float* g1   = (const float*)d_in[3];
    const float* be1  = (const float*)d_in[4];
    const float* rm1  = (const float*)d_in[5];
    const float* rv1  = (const float*)d_in[6];
    const float* Wl   = (const float*)d_in[7];
    const float* bl   = (const float*)d_in[8];
    const float* Wr   = (const float*)d_in[9];
    const float* br   = (const float*)d_in[10];
    const float* We   = (const float*)d_in[11];
    const float* att  = (const float*)d_in[12];
    const float* bias_gat = (const float*)d_in[13];
    const float* W1   = (const float*)d_in[14];
    const float* b1   = (const float*)d_in[15];
    const float* g2   = (const float*)d_in[16];
    const float* be2  = (const float*)d_in[17];
    const float* rm2  = (const float*)d_in[18];
    const float* rv2  = (const float*)d_in[19];
    const float* W2   = (const float*)d_in[20];
    const float* b2   = (const float*)d_in[21];

    float* ws  = (float*)d_ws;
    float* hbn = ws + OFF_HBN;
    float* acc = ws + OFF_ACC;

    hipMemsetAsync(acc, 0, (size_t)N_NODES * 16 * 4, stream);
    k_bn1<<<(N_NODES * 8 + 255) / 256, 256, 0, stream>>>(h, g1, be1, rm1, rv1, hbn);
    k_edge<<<1280, 256, 0, stream>>>(hbn, ei, ew, Wl, bl, Wr, br, We, att, acc);
    k_mlp<<<512, 256, 0, stream>>>(acc, Wl, bl, bias_gat, W1, b1, g2, be2, rm2, rv2, W2, b2,
                                   (float*)d_out);
}